// Round 6
// baseline (235.131 us; speedup 1.0000x reference)
//
#include <hip/hip_runtime.h>
#include <math.h>

typedef _Float16 half8_t  __attribute__((ext_vector_type(8)));
typedef _Float16 half4_t  __attribute__((ext_vector_type(4)));
typedef float    floatx16 __attribute__((ext_vector_type(16)));

#define BS   16
#define LL   2048
#define DIMC 512
#define NG   2
#define VD   256
#define NC   320
#define NELEM ((double)(VD*LL))   // 524288 per (b,g)

#define MFMA32 __builtin_amdgcn_mfma_f32_32x32x16_f16

// ---------------------------------------------------------------------------
// Two-kernel structure VERBATIM from the harness-passing 199.7us baseline:
// k_proj writes ze (f32) into out + f64 stats atomics; k_vq reads ze,
// normalizes, argmins, overwrites out with emb[idx]. The only change vs
// baseline: the k_prep launch is eliminated — each kernel builds its own
// f16 hi/lo split operand images in LDS directly from the small L2-resident
// W (256 KB) / emb (320 KB), with BIT-IDENTICAL split arithmetic, and k_vq
// computes e2 per block with k_prep's exact f64 4-partial pattern. Every
// stored value (ze, out, stats semantics) is bit-identical to baseline.
// Saves one graph node + its launch gap and 959 KB of workspace images.
// ---------------------------------------------------------------------------

// ---------------------------------------------------------------------------
// k_proj: ze = X * (16W)^T / 16, 3-term f16-split MFMA. Tile 128 pos x 256
// outdim (full group). 4 waves: (w&1) m-half of 64, (w>>1) n-half of 128.
// W chunk split built in-kernel (s = w*16.0f, exact pow2, == k_prep's image).
// LDS 55.3 KB -> 2 blocks/CU. fp64 stats per (b,g) via atomicAdd (baseline).
// ---------------------------------------------------------------------------
__global__ __launch_bounds__(256, 2) void k_proj(
    const float* __restrict__ x, const float* __restrict__ W,
    float* __restrict__ ze, double* __restrict__ stats)
{
  __shared__ _Float16 Ah[128][72];
  __shared__ _Float16 Bh[256 * 72];

  const int blk = blockIdx.x;
  const int g  = blk & 1;
  const int m0 = (blk >> 1) * 128;     // flat position b*2048+l
  const int b  = m0 >> 11;
  const int t  = threadIdx.x;
  const int lane = t & 63, w = t >> 6;
  const int col  = lane & 31, hq = lane >> 5;
  const int mw = (w & 1) * 64, nw = (w >> 1) * 128;

  const float* wg = W + (size_t)g * VD * VD;   // (256 out, 256 in)

  floatx16 acc[2][4];
  #pragma unroll
  for (int i = 0; i < 2; ++i)
    #pragma unroll
    for (int j = 0; j < 4; ++j)
      #pragma unroll
      for (int e = 0; e < 16; ++e) acc[i][j][e] = 0.f;

  for (int c = 0; c < 8; ++c) {
    // X chunk: 128 rows x 32 k, split to hi/lo (baseline-verbatim)
    #pragma unroll
    for (int i = 0; i < 4; ++i) {
      int idx = i * 256 + t;
      int row = idx >> 3, kq = idx & 7;
      float4 v = *(const float4*)(x + ((size_t)(m0 + row)) * DIMC + g * VD + c * 32 + kq * 4);
      half4_t hh, ll;
      { _Float16 h = (_Float16)v.x; hh[0] = h; ll[0] = (_Float16)(v.x - (float)h); }
      { _Float16 h = (_Float16)v.y; hh[1] = h; ll[1] = (_Float16)(v.y - (float)h); }
      { _Float16 h = (_Float16)v.z; hh[2] = h; ll[2] = (_Float16)(v.z - (float)h); }
      { _Float16 h = (_Float16)v.w; hh[3] = h; ll[3] = (_Float16)(v.w - (float)h); }
      *(half4_t*)&Ah[row][kq * 4]      = hh;
      *(half4_t*)&Ah[row][32 + kq * 4] = ll;
    }
    // W chunk split built in-kernel: 256 outdims x 32 k. 1024 8-elem quads.
    // s = w*16.0f (exact pow2) -> identical halves to k_prep's Wimg.
    #pragma unroll
    for (int i = 0; i < 4; ++i) {
      int idx = i * 256 + t;
      int o = idx >> 2, kk = (idx & 3) * 8;
      const float* wr = wg + (size_t)o * VD + c * 32 + kk;
      float4 v0 = *(const float4*)(wr);
      float4 v1 = *(const float4*)(wr + 4);
      float vv[8] = {v0.x, v0.y, v0.z, v0.w, v1.x, v1.y, v1.z, v1.w};
      half8_t hh, ll;
      #pragma unroll
      for (int u = 0; u < 8; ++u) {
        float s = vv[u] * 16.0f;
        _Float16 h = (_Float16)s;
        hh[u] = h; ll[u] = (_Float16)(s - (float)h);
      }
      *(half8_t*)&Bh[o * 72 + kk]      = hh;
      *(half8_t*)&Bh[o * 72 + 32 + kk] = ll;
    }
    __syncthreads();
    #pragma unroll
    for (int ks = 0; ks < 2; ++ks) {
      const int ko = ks * 16 + hq * 8;
      half8_t azh[2], azl[2], bwh[4], bwl[4];
      #pragma unroll
      for (int i = 0; i < 2; ++i) {
        azh[i] = *(const half8_t*)&Ah[mw + i * 32 + col][ko];
        azl[i] = *(const half8_t*)&Ah[mw + i * 32 + col][32 + ko];
      }
      #pragma unroll
      for (int j = 0; j < 4; ++j) {
        bwh[j] = *(const half8_t*)&Bh[(nw + j * 32 + col) * 72 + ko];
        bwl[j] = *(const half8_t*)&Bh[(nw + j * 32 + col) * 72 + 32 + ko];
      }
      #pragma unroll
      for (int mi = 0; mi < 2; ++mi)
        #pragma unroll
        for (int ni = 0; ni < 4; ++ni) {
          acc[mi][ni] = MFMA32(azh[mi], bwh[ni], acc[mi][ni], 0, 0, 0);
          acc[mi][ni] = MFMA32(azh[mi], bwl[ni], acc[mi][ni], 0, 0, 0);
          acc[mi][ni] = MFMA32(azl[mi], bwh[ni], acc[mi][ni], 0, 0, 0);
        }
    }
    __syncthreads();
  }

  // epilogue: scale back 1/16 (exact), fp64 stats, stores (baseline-verbatim)
  double s1 = 0.0, s2 = 0.0;
  #pragma unroll
  for (int mi = 0; mi < 2; ++mi)
    #pragma unroll
    for (int ni = 0; ni < 4; ++ni)
      #pragma unroll
      for (int r = 0; r < 16; ++r) {
        float vv = acc[mi][ni][r] * 0.0625f;
        double d = (double)vv; s1 += d; s2 += d * d;
        int ml = mw + mi * 32 + (r & 3) + 8 * (r >> 2) + 4 * hq;
        int nl = nw + ni * 32 + col;
        ze[((size_t)(m0 + ml)) * DIMC + g * VD + nl] = vv;
      }
  #pragma unroll
  for (int off = 32; off > 0; off >>= 1) {
    s1 += __shfl_down(s1, off);
    s2 += __shfl_down(s2, off);
  }
  if (lane == 0) {
    atomicAdd(&stats[(b * NG + g) * 2 + 0], s1);
    atomicAdd(&stats[(b * NG + g) * 2 + 1], s2);
  }
}

// ---------------------------------------------------------------------------
// k_vq: GroupNorm -> split -> flipped MFMA (A = E' codes, B = Z positions):
// D[code][pos], col=lane = pos -> fully in-lane argmin over 160 codes + one
// shfl_xor(32). Tile 128 pos x 320 codes; wave w owns pos-tile w*32.
// E' chunk split built in-kernel (s = e*64.0f, == k_prep's Eimg); e2 computed
// per block with k_prep's exact f64 4-partial pattern. mean/rstd finalized
// inline from plain stats loads (baseline-verbatim).
// Epilogue: out rows = emb[idx] directly (STE residue far below bf16 floor).
// ---------------------------------------------------------------------------
__global__ __launch_bounds__(256, 2) void k_vq(
    float* __restrict__ zio, const float* __restrict__ emb,
    const float* __restrict__ gnw, const float* __restrict__ gnb,
    const double* __restrict__ stats)
{
  __shared__ _Float16 Zs[128][72];
  __shared__ _Float16 Es[320 * 72];
  __shared__ float e2sh[NC];
  __shared__ int idxs[128];

  const int blk = blockIdx.x;
  const int g  = blk & 1;
  const int m0 = (blk >> 1) * 128;
  const int b  = m0 >> 11;
  const int t  = threadIdx.x;
  const int lane = t & 63, w = t >> 6;
  const int col  = lane & 31, hq = lane >> 5;

  // finalize stats inline (uniform per block; identical fp64 math every call)
  const int si = b * NG + g;
  double ss1 = stats[2 * si], ss2 = stats[2 * si + 1];
  double mu = ss1 / NELEM, var = ss2 / NELEM - mu * mu;
  const float mean = (float)mu;
  const float rstd = (float)(1.0 / sqrt(var + 1e-5));

  // e2 per block: k_prep's exact f64 4-partial pattern per code
  for (int code = t; code < NC; code += 256) {
    const float* er = emb + (size_t)code * VD;
    double s[4] = {0.0, 0.0, 0.0, 0.0};
    for (int v = 0; v < VD; v += 16)
      #pragma unroll
      for (int u = 0; u < 4; ++u) {
        float4 e4 = *(const float4*)(er + v + u * 4);
        s[u] += (double)e4.x * e4.x + (double)e4.y * e4.y
              + (double)e4.z * e4.z + (double)e4.w * e4.w;
      }
    e2sh[code] = (float)(64.0 * (s[0] + s[1] + s[2] + s[3]));
  }

  float* zbase = zio + (size_t)m0 * DIMC + g * VD;
  const float* gw = gnw + g * VD;
  const float* gb = gnb + g * VD;

  floatx16 acc[10];
  #pragma unroll
  for (int i = 0; i < 10; ++i)
    #pragma unroll
    for (int e = 0; e < 16; ++e) acc[i][e] = 0.f;

  for (int c = 0; c < 8; ++c) {
    // Z chunk: 128 rows x 32 k, GroupNorm + split (baseline-verbatim)
    #pragma unroll
    for (int i = 0; i < 4; ++i) {
      int idx = i * 256 + t;
      int row = idx >> 3, kq = idx & 7;
      float4 v  = *(const float4*)(zbase + (size_t)row * DIMC + c * 32 + kq * 4);
      float4 w4 = *(const float4*)(gw + c * 32 + kq * 4);
      float4 b4 = *(const float4*)(gb + c * 32 + kq * 4);
      float zn0 = (v.x - mean) * rstd * w4.x + b4.x;
      float zn1 = (v.y - mean) * rstd * w4.y + b4.y;
      float zn2 = (v.z - mean) * rstd * w4.z + b4.z;
      float zn3 = (v.w - mean) * rstd * w4.w + b4.w;
      half4_t hh, ll;
      { _Float16 h = (_Float16)zn0; hh[0] = h; ll[0] = (_Float16)(zn0 - (float)h); }
      { _Float16 h = (_Float16)zn1; hh[1] = h; ll[1] = (_Float16)(zn1 - (float)h); }
      { _Float16 h = (_Float16)zn2; hh[2] = h; ll[2] = (_Float16)(zn2 - (float)h); }
      { _Float16 h = (_Float16)zn3; hh[3] = h; ll[3] = (_Float16)(zn3 - (float)h); }
      *(half4_t*)&Zs[row][kq * 4]      = hh;
      *(half4_t*)&Zs[row][32 + kq * 4] = ll;
    }
    // E' chunk split built in-kernel: 320 codes x 32 k. 1280 8-elem quads.
    // s = e*64.0f (exact pow2) -> identical halves to k_prep's Eimg.
    #pragma unroll
    for (int i = 0; i < 5; ++i) {
      int idx = i * 256 + t;
      int code = idx >> 2, kk = (idx & 3) * 8;
      const float* er = emb + (size_t)code * VD + c * 32 + kk;
      float4 v0 = *(const float4*)(er);
      float4 v1 = *(const float4*)(er + 4);
      float vv[8] = {v0.x, v0.y, v0.z, v0.w, v1.x, v1.y, v1.z, v1.w};
      half8_t hh, ll;
      #pragma unroll
      for (int u = 0; u < 8; ++u) {
        float s = vv[u] * 64.0f;
        _Float16 h = (_Float16)s;
        hh[u] = h; ll[u] = (_Float16)(s - (float)h);
      }
      *(half8_t*)&Es[code * 72 + kk]      = hh;
      *(half8_t*)&Es[code * 72 + 32 + kk] = ll;
    }
    __syncthreads();
    #pragma unroll
    for (int ks = 0; ks < 2; ++ks) {
      const int ko = ks * 16 + hq * 8;
      half8_t bzh = *(const half8_t*)&Zs[w * 32 + col][ko];
      half8_t bzl = *(const half8_t*)&Zs[w * 32 + col][32 + ko];
      #pragma unroll
      for (int mt = 0; mt < 10; ++mt) {
        half8_t aeh = *(const half8_t*)&Es[(mt * 32 + col) * 72 + ko];
        half8_t ael = *(const half8_t*)&Es[(mt * 32 + col) * 72 + 32 + ko];
        acc[mt] = MFMA32(aeh, bzh, acc[mt], 0, 0, 0);
        acc[mt] = MFMA32(aeh, bzl, acc[mt], 0, 0, 0);
        acc[mt] = MFMA32(ael, bzh, acc[mt], 0, 0, 0);
      }
    }
    __syncthreads();
  }

  // in-lane argmin over 160 codes (lexicographic (d, code) = first-min), then
  // combine the hq pair with shfl_xor(32). Lane col of wave w owns pos w*32+col.
  float bv = 3.4e38f; int bi = 0x7fffffff;
  #pragma unroll
  for (int mt = 0; mt < 10; ++mt)
    #pragma unroll
    for (int r = 0; r < 16; ++r) {
      int code = mt * 32 + (r & 3) + 8 * (r >> 2) + 4 * hq;
      float d = e2sh[code] - 2.0f * acc[mt][r];
      if (d < bv || (d == bv && code < bi)) { bv = d; bi = code; }
    }
  {
    float ov = __shfl_xor(bv, 32);
    int   oi = __shfl_xor(bi, 32);
    if (ov < bv || (ov == bv && oi < bi)) { bv = ov; bi = oi; }
  }
  if (hq == 0) idxs[w * 32 + col] = bi;
  __syncthreads();

  // epilogue: out rows = emb[idx] (pure gather, no ze re-read)
  #pragma unroll
  for (int it = 0; it < 32; ++it) {
    int idx = it * 256 + t;             // 0..8191
    int row = idx >> 6, q4 = (idx & 63) * 4;
    int id = idxs[row];
    float4 e4 = *(const float4*)(emb + (size_t)id * VD + q4);
    *(float4*)(zbase + (size_t)row * DIMC + q4) = e4;
  }
}

extern "C" void kernel_launch(void* const* d_in, const int* in_sizes, int n_in,
                              void* d_out, int out_size, void* d_ws, size_t ws_size,
                              hipStream_t stream) {
  const float* x   = (const float*)d_in[0];
  const float* W   = (const float*)d_in[1];   // (2,256,256)
  const float* gnw = (const float*)d_in[2];   // (512,)
  const float* gnb = (const float*)d_in[3];   // (512,)
  const float* emb = (const float*)d_in[4];   // (320,1,256)
  float* out = (float*)d_out;

  double* stats = (double*)d_ws;              // 512 B total workspace use

  hipMemsetAsync(d_ws, 0, 512, stream);
  k_proj<<<512, 256, 0, stream>>>(x, W, out, stats);
  k_vq<<<512, 256, 0, stream>>>(out, emb, gnw, gnb, stats);
}

// Round 7
// 197.020 us; speedup vs baseline: 1.1934x; 1.1934x over previous
//
#include <hip/hip_runtime.h>
#include <math.h>

typedef _Float16 half8_t  __attribute__((ext_vector_type(8)));
typedef _Float16 half4_t  __attribute__((ext_vector_type(4)));
typedef float    floatx16 __attribute__((ext_vector_type(16)));

#define BS   16
#define LL   2048
#define DIMC 512
#define NG   2
#define VD   256
#define NC   320
#define NELEM ((double)(VD*LL))   // 524288 per (b,g)

// global -> LDS direct DMA, 16 B per lane. gsrc per-lane, ldst wave-uniform.
#define GLL(gsrc, ldst) __builtin_amdgcn_global_load_lds( \
    (const __attribute__((address_space(1))) unsigned int*)(gsrc), \
    (__attribute__((address_space(3))) unsigned int*)(ldst), 16, 0, 0)

#define MFMA32 __builtin_amdgcn_mfma_f32_32x32x16_f16

// ---------------------------------------------------------------------------
// k_prep: VERBATIM the round-0 passing kernel. Chunk-image f16 hi/lo splits
// of 16*W and 64*E, coalesced. Rows of 72 halves = 144 B: hi[32] lo[32] pad.
//   Wimg[g][chunk 8][row 256][72]
//   Eimg[chunk 8][code 320][72]
// Blocks 0..63: W. 64..103: E. 104..105: e2f. Pow2 scales are exact.
// ---------------------------------------------------------------------------
__global__ void k_prep(const float* __restrict__ W, const float* __restrict__ emb,
                       _Float16* __restrict__ Wimg, _Float16* __restrict__ Eimg,
                       float* __restrict__ e2f)
{
  const int blk = blockIdx.x, t = threadIdx.x;
  if (blk < 64) {
    int base = (blk * 256 + t) * 8;        // flat (g,o,v), 8 contiguous
    int k = base & 255, c = k >> 5, kk = k & 31;   // kk in {0,8,16,24}
    int row = (base >> 8) & 255, g = base >> 16;
    float4 v0 = *(const float4*)(W + base);
    float4 v1 = *(const float4*)(W + base + 4);
    float vv[8] = {v0.x, v0.y, v0.z, v0.w, v1.x, v1.y, v1.z, v1.w};
    half8_t hh, ll;
    #pragma unroll
    for (int i = 0; i < 8; ++i) {
      float s = vv[i] * 16.0f;
      _Float16 h = (_Float16)s;
      hh[i] = h; ll[i] = (_Float16)(s - (float)h);
    }
    size_t rb = ((size_t)(g * 8 + c) * 256 + row) * 72;
    *(half8_t*)&Wimg[rb + kk]      = hh;
    *(half8_t*)&Wimg[rb + 32 + kk] = ll;
  } else if (blk < 104) {
    int base = ((blk - 64) * 256 + t) * 8; // flat (code,v)
    int k = base & 255, c = k >> 5, kk = k & 31;
    int code = base >> 8;
    float4 v0 = *(const float4*)(emb + base);
    float4 v1 = *(const float4*)(emb + base + 4);
    float vv[8] = {v0.x, v0.y, v0.z, v0.w, v1.x, v1.y, v1.z, v1.w};
    half8_t hh, ll;
    #pragma unroll
    for (int i = 0; i < 8; ++i) {
      float s = vv[i] * 64.0f;
      _Float16 h = (_Float16)s;
      hh[i] = h; ll[i] = (_Float16)(s - (float)h);
    }
    size_t rb = ((size_t)c * 320 + code) * 72;
    *(half8_t*)&Eimg[rb + kk]      = hh;
    *(half8_t*)&Eimg[rb + 32 + kk] = ll;
  } else {
    int code = (blk - 104) * 256 + t;
    if (code < NC) {
      const float* er = emb + (size_t)code * VD;
      double s[4] = {0.0, 0.0, 0.0, 0.0};
      for (int v = 0; v < VD; v += 16)
        #pragma unroll
        for (int u = 0; u < 4; ++u) {
          float4 e4 = *(const float4*)(er + v + u * 4);
          s[u] += (double)e4.x * e4.x + (double)e4.y * e4.y
                + (double)e4.z * e4.z + (double)e4.w * e4.w;
        }
      e2f[code] = (float)(64.0 * (s[0] + s[1] + s[2] + s[3]));
    }
  }
}

// ---------------------------------------------------------------------------
// k_proj: VERBATIM round-0 except the W-image GLL is issued BEFORE the X
// split staging so the DMA latency hides under the split VALU work (both
// write disjoint LDS regions and drain at the same barrier).
// ---------------------------------------------------------------------------
__global__ __launch_bounds__(256, 2) void k_proj(
    const float* __restrict__ x, const _Float16* __restrict__ Wimg,
    float* __restrict__ ze, double* __restrict__ stats)
{
  __shared__ _Float16 Ah[128][72];
  __shared__ _Float16 Bh[256 * 72];

  const int blk = blockIdx.x;
  const int g  = blk & 1;
  const int m0 = (blk >> 1) * 128;     // flat position b*2048+l
  const int b  = m0 >> 11;
  const int t  = threadIdx.x;
  const int lane = t & 63, w = t >> 6;
  const int col  = lane & 31, hq = lane >> 5;
  const int mw = (w & 1) * 64, nw = (w >> 1) * 128;

  const char* wbase = (const char*)(Wimg + (size_t)g * 8 * 256 * 72);

  floatx16 acc[2][4];
  #pragma unroll
  for (int i = 0; i < 2; ++i)
    #pragma unroll
    for (int j = 0; j < 4; ++j)
      #pragma unroll
      for (int e = 0; e < 16; ++e) acc[i][j][e] = 0.f;

  for (int c = 0; c < 8; ++c) {
    // W chunk image first: 36864 B via global_load_lds (9 per wave) — in
    // flight while the X split below runs on the VALU.
    {
      const char* wc = wbase + (size_t)c * 256 * 144;
      #pragma unroll
      for (int i = 0; i < 9; ++i) {
        int off = (w * 9 + i) * 1024 + lane * 16;
        GLL(wc + off, (char*)Bh + off);
      }
    }
    // X chunk: 128 rows x 32 k, split to hi/lo
    #pragma unroll
    for (int i = 0; i < 4; ++i) {
      int idx = i * 256 + t;
      int row = idx >> 3, kq = idx & 7;
      float4 v = *(const float4*)(x + ((size_t)(m0 + row)) * DIMC + g * VD + c * 32 + kq * 4);
      half4_t hh, ll;
      { _Float16 h = (_Float16)v.x; hh[0] = h; ll[0] = (_Float16)(v.x - (float)h); }
      { _Float16 h = (_Float16)v.y; hh[1] = h; ll[1] = (_Float16)(v.y - (float)h); }
      { _Float16 h = (_Float16)v.z; hh[2] = h; ll[2] = (_Float16)(v.z - (float)h); }
      { _Float16 h = (_Float16)v.w; hh[3] = h; ll[3] = (_Float16)(v.w - (float)h); }
      *(half4_t*)&Ah[row][kq * 4]      = hh;
      *(half4_t*)&Ah[row][32 + kq * 4] = ll;
    }
    __syncthreads();
    #pragma unroll
    for (int ks = 0; ks < 2; ++ks) {
      const int ko = ks * 16 + hq * 8;
      half8_t azh[2], azl[2], bwh[4], bwl[4];
      #pragma unroll
      for (int i = 0; i < 2; ++i) {
        azh[i] = *(const half8_t*)&Ah[mw + i * 32 + col][ko];
        azl[i] = *(const half8_t*)&Ah[mw + i * 32 + col][32 + ko];
      }
      #pragma unroll
      for (int j = 0; j < 4; ++j) {
        bwh[j] = *(const half8_t*)&Bh[(nw + j * 32 + col) * 72 + ko];
        bwl[j] = *(const half8_t*)&Bh[(nw + j * 32 + col) * 72 + 32 + ko];
      }
      #pragma unroll
      for (int mi = 0; mi < 2; ++mi)
        #pragma unroll
        for (int ni = 0; ni < 4; ++ni) {
          acc[mi][ni] = MFMA32(azh[mi], bwh[ni], acc[mi][ni], 0, 0, 0);
          acc[mi][ni] = MFMA32(azh[mi], bwl[ni], acc[mi][ni], 0, 0, 0);
          acc[mi][ni] = MFMA32(azl[mi], bwh[ni], acc[mi][ni], 0, 0, 0);
        }
    }
    __syncthreads();
  }

  // epilogue: scale back 1/16 (exact), fp64 stats, stores (round-0 verbatim)
  double s1 = 0.0, s2 = 0.0;
  #pragma unroll
  for (int mi = 0; mi < 2; ++mi)
    #pragma unroll
    for (int ni = 0; ni < 4; ++ni)
      #pragma unroll
      for (int r = 0; r < 16; ++r) {
        float vv = acc[mi][ni][r] * 0.0625f;
        double d = (double)vv; s1 += d; s2 += d * d;
        int ml = mw + mi * 32 + (r & 3) + 8 * (r >> 2) + 4 * hq;
        int nl = nw + ni * 32 + col;
        ze[((size_t)(m0 + ml)) * DIMC + g * VD + nl] = vv;
      }
  #pragma unroll
  for (int off = 32; off > 0; off >>= 1) {
    s1 += __shfl_down(s1, off);
    s2 += __shfl_down(s2, off);
  }
  if (lane == 0) {
    atomicAdd(&stats[(b * NG + g) * 2 + 0], s1);
    atomicAdd(&stats[(b * NG + g) * 2 + 1], s2);
  }
}

// ---------------------------------------------------------------------------
// k_vq: round-0 algorithm with a rebalanced wave->tile map to cut LDS read
// BW (the measured bottleneck: 44 ds_read_b128 per wave-chunk vs 60 MFMA,
// with all 4 waves reading the SAME Es fragments). New map: (w&1)=pos-half
// (2 B-fragments of 32 pos), (w>>1)=mt-half (5 of 10 code tiles) -> per-wave
// reads/chunk 44 -> 28 at the same 60 MFMA. Each accumulator receives the
// IDENTICAL MFMA chain (same operand values, same c/ks/3-term order), and
// argmin is a partition-invariant lexicographic min recombined through a
// deterministic LDS reduction -> output bit-identical to round-0.
// Es GLL issued before the Z-normalize staging (latency hidden under VALU).
// ---------------------------------------------------------------------------
__global__ __launch_bounds__(256, 2) void k_vq(
    float* __restrict__ zio, const float* __restrict__ emb,
    const _Float16* __restrict__ Eimg,
    const float* __restrict__ gnw, const float* __restrict__ gnb,
    const double* __restrict__ stats, const float* __restrict__ e2f)
{
  __shared__ _Float16 Zs[128][72];
  __shared__ _Float16 Es[320 * 72];
  __shared__ float e2sh[NC];
  __shared__ int   idxs[128];
  __shared__ float cndv[2][128];
  __shared__ int   cndi[2][128];

  const int blk = blockIdx.x;
  const int g  = blk & 1;
  const int m0 = (blk >> 1) * 128;
  const int b  = m0 >> 11;
  const int t  = threadIdx.x;
  const int lane = t & 63, w = t >> 6;
  const int col  = lane & 31, hq = lane >> 5;
  const int ph = w & 1;                // pos-half: rows ph*64 .. ph*64+63
  const int mh = w >> 1;               // mt-half: tiles mh*5 .. mh*5+4

  // finalize stats inline (uniform per block; identical fp64 math every call)
  const int si = b * NG + g;
  double ss1 = stats[2 * si], ss2 = stats[2 * si + 1];
  double mu = ss1 / NELEM, var = ss2 / NELEM - mu * mu;
  const float mean = (float)mu;
  const float rstd = (float)(1.0 / sqrt(var + 1e-5));

  for (int c = t; c < NC; c += 256) e2sh[c] = e2f[c];

  float* zbase = zio + (size_t)m0 * DIMC + g * VD;
  const float* gw = gnw + g * VD;
  const float* gb = gnb + g * VD;

  floatx16 acc[5][2];
  #pragma unroll
  for (int i = 0; i < 5; ++i)
    #pragma unroll
    for (int f = 0; f < 2; ++f)
      #pragma unroll
      for (int e = 0; e < 16; ++e) acc[i][f][e] = 0.f;

  for (int c = 0; c < 8; ++c) {
    // E' chunk image first: 46080 B via global_load_lds (45 wave-loads) —
    // in flight while the GroupNorm+split below runs on the VALU.
    {
      const char* ec = (const char*)Eimg + (size_t)c * 320 * 144;
      for (int i = w; i < 45; i += 4) {
        int off = i * 1024 + lane * 16;
        GLL(ec + off, (char*)Es + off);
      }
    }
    // Z chunk: 128 rows x 32 k, GroupNorm + split (round-0 verbatim)
    #pragma unroll
    for (int i = 0; i < 4; ++i) {
      int idx = i * 256 + t;
      int row = idx >> 3, kq = idx & 7;
      float4 v  = *(const float4*)(zbase + (size_t)row * DIMC + c * 32 + kq * 4);
      float4 w4 = *(const float4*)(gw + c * 32 + kq * 4);
      float4 b4 = *(const float4*)(gb + c * 32 + kq * 4);
      float zn0 = (v.x - mean) * rstd * w4.x + b4.x;
      float zn1 = (v.y - mean) * rstd * w4.y + b4.y;
      float zn2 = (v.z - mean) * rstd * w4.z + b4.z;
      float zn3 = (v.w - mean) * rstd * w4.w + b4.w;
      half4_t hh, ll;
      { _Float16 h = (_Float16)zn0; hh[0] = h; ll[0] = (_Float16)(zn0 - (float)h); }
      { _Float16 h = (_Float16)zn1; hh[1] = h; ll[1] = (_Float16)(zn1 - (float)h); }
      { _Float16 h = (_Float16)zn2; hh[2] = h; ll[2] = (_Float16)(zn2 - (float)h); }
      { _Float16 h = (_Float16)zn3; hh[3] = h; ll[3] = (_Float16)(zn3 - (float)h); }
      *(half4_t*)&Zs[row][kq * 4]      = hh;
      *(half4_t*)&Zs[row][32 + kq * 4] = ll;
    }
    __syncthreads();
    #pragma unroll
    for (int ks = 0; ks < 2; ++ks) {
      const int ko = ks * 16 + hq * 8;
      half8_t bzh[2], bzl[2];
      #pragma unroll
      for (int f = 0; f < 2; ++f) {
        bzh[f] = *(const half8_t*)&Zs[ph * 64 + f * 32 + col][ko];
        bzl[f] = *(const half8_t*)&Zs[ph * 64 + f * 32 + col][32 + ko];
      }
      #pragma unroll
      for (int mtl = 0; mtl < 5; ++mtl) {
        const _Float16* erow = &Es[((mh * 5 + mtl) * 32 + col) * 72];
        half8_t aeh = *(const half8_t*)&erow[ko];
        half8_t ael = *(const half8_t*)&erow[32 + ko];
        #pragma unroll
        for (int f = 0; f < 2; ++f) {
          acc[mtl][f] = MFMA32(aeh, bzh[f], acc[mtl][f], 0, 0, 0);
          acc[mtl][f] = MFMA32(aeh, bzl[f], acc[mtl][f], 0, 0, 0);
          acc[mtl][f] = MFMA32(ael, bzh[f], acc[mtl][f], 0, 0, 0);
        }
      }
    }
    __syncthreads();
  }

  // argmin: in-lane over 5 tiles x 16 regs per pos-fragment (lexicographic
  // (d, code) min), combine hq pair via shfl_xor(32), then combine the two
  // mt-half waves through LDS in fixed order. Partition-invariant == round-0.
  float bv0 = 3.4e38f, bv1 = 3.4e38f;
  int   bi0 = 0x7fffffff, bi1 = 0x7fffffff;
  #pragma unroll
  for (int mtl = 0; mtl < 5; ++mtl)
    #pragma unroll
    for (int r = 0; r < 16; ++r) {
      int code = (mh * 5 + mtl) * 32 + (r & 3) + 8 * (r >> 2) + 4 * hq;
      float d0 = e2sh[code] - 2.0f * acc[mtl][0][r];
      if (d0 < bv0 || (d0 == bv0 && code < bi0)) { bv0 = d0; bi0 = code; }
      float d1 = e2sh[code] - 2.0f * acc[mtl][1][r];
      if (d1 < bv1 || (d1 == bv1 && code < bi1)) { bv1 = d1; bi1 = code; }
    }
  {
    float ov = __shfl_xor(bv0, 32); int oi = __shfl_xor(bi0, 32);
    if (ov < bv0 || (ov == bv0 && oi < bi0)) { bv0 = ov; bi0 = oi; }
    ov = __shfl_xor(bv1, 32); oi = __shfl_xor(bi1, 32);
    if (ov < bv1 || (ov == bv1 && oi < bi1)) { bv1 = ov; bi1 = oi; }
  }
  if (hq == 0) {
    cndv[mh][ph * 64 + col]      = bv0; cndi[mh][ph * 64 + col]      = bi0;
    cndv[mh][ph * 64 + 32 + col] = bv1; cndi[mh][ph * 64 + 32 + col] = bi1;
  }
  __syncthreads();
  if (t < 128) {
    float v0 = cndv[0][t], v1 = cndv[1][t];
    int   i0 = cndi[0][t], i1 = cndi[1][t];
    idxs[t] = (v1 < v0 || (v1 == v0 && i1 < i0)) ? i1 : i0;
  }
  __syncthreads();

  // epilogue: out rows = emb[idx] (pure gather, no ze re-read; round-0)
  #pragma unroll
  for (int it = 0; it < 32; ++it) {
    int idx = it * 256 + t;             // 0..8191
    int row = idx >> 6, q4 = (idx & 63) * 4;
    int id = idxs[row];
    float4 e4 = *(const float4*)(emb + (size_t)id * VD + q4);
    *(float4*)(zbase + (size_t)row * DIMC + q4) = e4;
  }
}

extern "C" void kernel_launch(void* const* d_in, const int* in_sizes, int n_in,
                              void* d_out, int out_size, void* d_ws, size_t ws_size,
                              hipStream_t stream) {
  const float* x   = (const float*)d_in[0];
  const float* W   = (const float*)d_in[1];   // (2,256,256)
  const float* gnw = (const float*)d_in[2];   // (512,)
  const float* gnb = (const float*)d_in[3];   // (512,)
  const float* emb = (const float*)d_in[4];   // (320,1,256)
  float* out = (float*)d_out;

  double*   stats = (double*)d_ws;                       // 512 B
  float*    e2f   = (float*)((char*)d_ws + 512);         // 1280 B
  _Float16* Wimg  = (_Float16*)((char*)d_ws + 2048);     // 589824 B
  _Float16* Eimg  = (_Float16*)((char*)d_ws + 591872);   // 368640 B -> 960512 total

  hipMemsetAsync(d_ws, 0, 512, stream);
  k_prep<<<106, 256, 0, stream>>>(W, emb, Wimg, Eimg, e2f);
  k_proj<<<512, 256, 0, stream>>>(x, Wimg, out, stats);
  k_vq<<<512, 256, 0, stream>>>(out, emb, Eimg, gnw, gnb, stats, e2f);
}